// Round 4
// baseline (451.171 us; speedup 1.0000x reference)
//
#include <hip/hip_runtime.h>
#include <hip/hip_bf16.h>

#define N_NODES 50000
#define N_EDGES 800000
#define NPAD    50048          // 782 * 64, so GEMM A-staging never reads OOB
#define IN_DIM  100
#define HID     128
#define BN_EPS  1e-5f

#define BSHIFT  6
#define BUCKS   782            // ceil(50000 / 64)
#define BCAP    2048           // LDS edge capacity per bucket (mean 1024, sigma 32)

typedef unsigned int uint;
typedef unsigned short u16;
typedef __attribute__((ext_vector_type(8))) unsigned short us8;
typedef __attribute__((ext_vector_type(8))) short s8;      // bf16 MFMA frag
typedef __attribute__((ext_vector_type(4))) float f4;

__device__ __forceinline__ u16 f2bf(float f) {
    uint u = __builtin_bit_cast(uint, f);
    uint r = (u + 0x7FFFu + ((u >> 16) & 1u)) >> 16;   // RNE
    return (u16)r;
}
__device__ __forceinline__ uint pack2(float a, float b) {
    return (uint)f2bf(a) | ((uint)f2bf(b) << 16);
}
__device__ __forceinline__ float bflo(uint p) { return __builtin_bit_cast(float, p << 16); }
__device__ __forceinline__ float bfhi(uint p) { return __builtin_bit_cast(float, p & 0xFFFF0000u); }

// ---------------------------------------------------------------------------
// Bucketed edge organization (replaces global CSR build)
// ---------------------------------------------------------------------------
// per-block LDS histogram of dst>>6 -> global bucket counts
__global__ __launch_bounds__(1024) void bucket_hist(const int* __restrict__ dst,
                                                    int* __restrict__ bcount) {
    __shared__ int h[BUCKS];
    int t = threadIdx.x;
    for (int i = t; i < BUCKS; i += 1024) h[i] = 0;
    __syncthreads();
    int base = blockIdx.x * 8192;
    #pragma unroll
    for (int r = 0; r < 8; ++r) {
        int e = base + r * 1024 + t;
        if (e < N_EDGES) atomicAdd(&h[dst[e] >> BSHIFT], 1);
    }
    __syncthreads();
    for (int i = t; i < BUCKS; i += 1024) {
        int v = h[i];
        if (v) atomicAdd(&bcount[i], v);
    }
}

// single block: exclusive scan of BUCKS counts -> bbase[0..BUCKS], bcursor
__global__ __launch_bounds__(1024) void scan_buckets(const int* __restrict__ bcount,
                                                     int* __restrict__ bbase,
                                                     int* __restrict__ bcursor) {
    __shared__ int ws[16];
    int t = threadIdx.x, lane = t & 63, wv = t >> 6;
    int v = (t < BUCKS) ? bcount[t] : 0;
    int s = v;
    #pragma unroll
    for (int off = 1; off < 64; off <<= 1) {
        int u = __shfl_up(s, off, 64);
        if (lane >= off) s += u;
    }
    if (lane == 63) ws[wv] = s;
    __syncthreads();
    if (wv == 0) {
        int w = (lane < 16) ? ws[lane] : 0;
        #pragma unroll
        for (int off = 1; off < 16; off <<= 1) {
            int u = __shfl_up(w, off, 64);
            if (lane >= off) w += u;
        }
        if (lane < 16) ws[lane] = w;
    }
    __syncthreads();
    int excl = s - v + ((wv == 0) ? 0 : ws[wv - 1]);
    if (t < BUCKS) { bbase[t] = excl; bcursor[t] = excl; }
    if (t == 0) bbase[BUCKS] = N_EDGES;
}

// scatter packed edges (src | local_dst<<16) into bucket-contiguous ebuf
__global__ void bucket_scatter(const int* __restrict__ src, const int* __restrict__ dst,
                               int* __restrict__ bcursor, uint* __restrict__ ebuf) {
    int e = blockIdx.x * 256 + threadIdx.x;
    if (e < N_EDGES) {
        int d = dst[e];
        int pos = atomicAdd(&bcursor[d >> BSHIFT], 1);
        ebuf[pos] = (uint)src[e] | ((uint)(d & 63) << 16);
    }
}

// ---------------------------------------------------------------------------
// Casts to bf16
// ---------------------------------------------------------------------------
__global__ void cast_x_kernel(const float* __restrict__ x, u16* __restrict__ xb) {
    int idx = blockIdx.x * blockDim.x + threadIdx.x;
    if (idx >= N_NODES * 128) return;
    int row = idx >> 7, k = idx & 127;
    float v = (k < IN_DIM) ? x[row * IN_DIM + k] : 0.f;
    xb[idx] = f2bf(v);
}

// weights: fp32 [Ksrc][128] -> bf16 transposed [128 n][128 k], zero-padded k
__global__ void cast_w_kernel(const float* __restrict__ W_l0, const float* __restrict__ W_r0,
                              const float* __restrict__ W_l1, const float* __restrict__ W_r1,
                              u16* __restrict__ d) {
    int w = blockIdx.y;
    const float* s = (w == 0) ? W_l0 : (w == 1) ? W_r0 : (w == 2) ? W_l1 : W_r1;
    int Ks = (w < 2) ? IN_DIM : HID;
    int idx = blockIdx.x * 256 + threadIdx.x;   // 0..16383
    int n = idx >> 7, k = idx & 127;
    float v = (k < Ks) ? s[k * 128 + n] : 0.f;
    d[w * 16384 + idx] = f2bf(v);
}

// ---------------------------------------------------------------------------
// Fused bucket-local CSR + mean aggregation.
// Block = 512 thr (8 waves) = one bucket of 64 nodes. LDS CSR from ebuf slice,
// then wave-per-node quad-parallel gather (16B/lane uint4 loads).
// ---------------------------------------------------------------------------
__global__ __launch_bounds__(512) void agg_fused(
    const uint* __restrict__ ebuf, const int* __restrict__ bbase,
    const u16* __restrict__ X, u16* __restrict__ out) {
    __shared__ uint eL[BCAP];
    __shared__ u16 srcL[BCAP];
    __shared__ int cnt[64], ro[65], cur[64];

    int b = blockIdx.x;
    int t = threadIdx.x;
    int beg = bbase[b], end = bbase[b + 1];
    int n = end - beg;
    if (n > BCAP) n = BCAP;   // statistically unreachable (mean 1024, cap 32 sigma)

    if (t < 64) cnt[t] = 0;
    __syncthreads();
    for (int i = t; i < n; i += 512) {
        uint p = ebuf[beg + i];
        eL[i] = p;
        atomicAdd(&cnt[p >> 16], 1);
    }
    __syncthreads();
    if (t < 64) {
        int v = cnt[t];
        int s = v;
        #pragma unroll
        for (int off = 1; off < 64; off <<= 1) {
            int u = __shfl_up(s, off, 64);
            if (t >= off) s += u;
        }
        ro[t] = s - v;
        cur[t] = s - v;
        if (t == 63) ro[64] = s;
    }
    __syncthreads();
    for (int i = t; i < n; i += 512) {
        uint p = eL[i];
        int pos = atomicAdd(&cur[p >> 16], 1);
        srcL[pos] = (u16)(p & 0xFFFFu);
    }
    __syncthreads();

    int wave = t >> 6, lane = t & 63;
    int quad = lane >> 4, sub = lane & 15;
    #pragma unroll
    for (int ni = 0; ni < 8; ++ni) {
        int nl = wave * 8 + ni;
        int node = b * 64 + nl;
        if (node >= N_NODES) continue;   // wave-uniform
        int rb = ro[nl], re = ro[nl + 1];

        float a0 = 0.f, a1 = 0.f, a2 = 0.f, a3 = 0.f;
        float a4 = 0.f, a5 = 0.f, a6 = 0.f, a7 = 0.f;
        int e = rb;
        for (; e + 8 <= re; e += 8) {
            int s0 = srcL[e + quad];          // LDS broadcast within quad
            int s1 = srcL[e + 4 + quad];
            uint4 v0 = ((const uint4*)(X + (size_t)s0 * 128))[sub];
            uint4 v1 = ((const uint4*)(X + (size_t)s1 * 128))[sub];
            a0 += bflo(v0.x) + bflo(v1.x);
            a1 += bfhi(v0.x) + bfhi(v1.x);
            a2 += bflo(v0.y) + bflo(v1.y);
            a3 += bfhi(v0.y) + bfhi(v1.y);
            a4 += bflo(v0.z) + bflo(v1.z);
            a5 += bfhi(v0.z) + bfhi(v1.z);
            a6 += bflo(v0.w) + bflo(v1.w);
            a7 += bfhi(v0.w) + bfhi(v1.w);
        }
        for (; e < re; e += 4) {
            int ee = e + quad;
            if (ee < re) {
                int s0 = srcL[ee];
                uint4 v0 = ((const uint4*)(X + (size_t)s0 * 128))[sub];
                a0 += bflo(v0.x); a1 += bfhi(v0.x);
                a2 += bflo(v0.y); a3 += bfhi(v0.y);
                a4 += bflo(v0.z); a5 += bfhi(v0.z);
                a6 += bflo(v0.w); a7 += bfhi(v0.w);
            }
        }
        #pragma unroll
        for (int m = 16; m <= 32; m <<= 1) {
            a0 += __shfl_xor(a0, m, 64); a1 += __shfl_xor(a1, m, 64);
            a2 += __shfl_xor(a2, m, 64); a3 += __shfl_xor(a3, m, 64);
            a4 += __shfl_xor(a4, m, 64); a5 += __shfl_xor(a5, m, 64);
            a6 += __shfl_xor(a6, m, 64); a7 += __shfl_xor(a7, m, 64);
        }
        if (quad == 0) {
            float inv = 1.0f / fmaxf((float)(re - rb), 1.0f);
            uint4 o;
            o.x = pack2(a0 * inv, a1 * inv);
            o.y = pack2(a2 * inv, a3 * inv);
            o.z = pack2(a4 * inv, a5 * inv);
            o.w = pack2(a6 * inv, a7 * inv);
            ((uint4*)(out + (size_t)node * 128))[sub] = o;
        }
    }
}

// ---------------------------------------------------------------------------
// Dual-input bf16 MFMA GEMM (unchanged; verified fast)
// ---------------------------------------------------------------------------
__global__ __launch_bounds__(256) void gemm_mfma(
    const u16* __restrict__ A1, const u16* __restrict__ A2,
    const u16* __restrict__ Wt1, const u16* __restrict__ Wt2,
    const float* __restrict__ bias, float* __restrict__ out, int M) {
    __shared__ u16 Als[64][32];
    __shared__ u16 Bls[128][32];

    int tid = threadIdx.x;
    int wave = tid >> 6;
    int lane = tid & 63;
    int l16 = lane & 15;
    int quad = lane >> 4;
    int rm = (wave & 1) * 32;
    int cn = (wave >> 1) * 64;
    int row0 = blockIdx.x * 64;

    f4 acc[2][4];
    #pragma unroll
    for (int i = 0; i < 2; i++)
        #pragma unroll
        for (int j = 0; j < 4; j++)
            acc[i][j] = (f4)0.f;

    #pragma unroll
    for (int phase = 0; phase < 2; ++phase) {
        const u16* A  = phase ? A2 : A1;
        const u16* Wt = phase ? Wt2 : Wt1;
        #pragma unroll
        for (int k0 = 0; k0 < 128; k0 += 32) {
            __syncthreads();
            {
                int r = tid >> 2, c = tid & 3;
                us8 v = *(const us8*)(A + (size_t)(row0 + r) * 128 + k0 + c * 8);
                *(us8*)&Als[r][c * 8] = v;
            }
            #pragma unroll
            for (int rep = 0; rep < 2; ++rep) {
                int idx = rep * 256 + tid;
                int nn = idx >> 2, c = idx & 3;
                us8 v = *(const us8*)(Wt + nn * 128 + k0 + c * 8);
                *(us8*)&Bls[nn][c * 8] = v;
            }
            __syncthreads();
            s8 af[2], bfr[4];
            #pragma unroll
            for (int mt = 0; mt < 2; ++mt)
                af[mt] = *(const s8*)&Als[rm + mt * 16 + l16][quad * 8];
            #pragma unroll
            for (int nt = 0; nt < 4; ++nt)
                bfr[nt] = *(const s8*)&Bls[cn + nt * 16 + l16][quad * 8];
            #pragma unroll
            for (int mt = 0; mt < 2; ++mt)
                #pragma unroll
                for (int nt = 0; nt < 4; ++nt)
                    acc[mt][nt] = __builtin_amdgcn_mfma_f32_16x16x32_bf16(
                        af[mt], bfr[nt], acc[mt][nt], 0, 0, 0);
        }
    }

    #pragma unroll
    for (int mt = 0; mt < 2; ++mt) {
        #pragma unroll
        for (int nt = 0; nt < 4; ++nt) {
            int col = cn + nt * 16 + l16;
            float b = bias[col];
            #pragma unroll
            for (int r = 0; r < 4; ++r) {
                int row = row0 + rm + mt * 16 + quad * 4 + r;
                if (row < M)
                    out[(size_t)row * 128 + col] = acc[mt][nt][r] + b;
            }
        }
    }
}

// ---------------------------------------------------------------------------
// BatchNorm stats: float4 reads, LDS tree, 8 atomics per block
// ---------------------------------------------------------------------------
__global__ void stats_kernel(const float* __restrict__ h, float* __restrict__ stats, int M) {
    __shared__ float l1[256 * 4], l2[256 * 4];
    int t = threadIdx.x;             // 256
    int tg = t >> 5, c = t & 31;
    float s1x = 0.f, s1y = 0.f, s1z = 0.f, s1w = 0.f;
    float s2x = 0.f, s2y = 0.f, s2z = 0.f, s2w = 0.f;
    for (int n = blockIdx.x * 8 + tg; n < M; n += gridDim.x * 8) {
        float4 v = ((const float4*)(h + (size_t)n * 128))[c];
        s1x += v.x; s1y += v.y; s1z += v.z; s1w += v.w;
        s2x = fmaf(v.x, v.x, s2x); s2y = fmaf(v.y, v.y, s2y);
        s2z = fmaf(v.z, v.z, s2z); s2w = fmaf(v.w, v.w, s2w);
    }
    l1[t * 4 + 0] = s1x; l1[t * 4 + 1] = s1y; l1[t * 4 + 2] = s1z; l1[t * 4 + 3] = s1w;
    l2[t * 4 + 0] = s2x; l2[t * 4 + 1] = s2y; l2[t * 4 + 2] = s2z; l2[t * 4 + 3] = s2w;
    __syncthreads();
    #pragma unroll
    for (int stride = 128; stride >= 64; stride >>= 1) {
        if (t < stride) {
            #pragma unroll
            for (int j = 0; j < 4; j++) {
                l1[t * 4 + j] += l1[(t + stride) * 4 + j];
                l2[t * 4 + j] += l2[(t + stride) * 4 + j];
            }
        }
        __syncthreads();
    }
    if (t < 32) {
        #pragma unroll
        for (int j = 0; j < 4; j++) {
            float v1 = l1[t * 4 + j] + l1[(t + 32) * 4 + j];
            float v2 = l2[t * 4 + j] + l2[(t + 32) * 4 + j];
            atomicAdd(&stats[t * 4 + j], v1);
            atomicAdd(&stats[128 + t * 4 + j], v2);
        }
    }
}

// BN(+ReLU)+cast to bf16, finalize inlined (layer-0 -> layer-1 handoff)
__global__ void bn_relu_cast_kernel(const float* __restrict__ h,
                                    const float* __restrict__ stats,
                                    const float* __restrict__ gamma,
                                    const float* __restrict__ beta,
                                    u16* __restrict__ hb, float inv_n, int total4) {
    __shared__ float ss[256];
    int t = threadIdx.x;
    if (t < 128) {
        float mean = stats[t] * inv_n;
        float var = stats[128 + t] * inv_n - mean * mean;
        float inv = 1.0f / sqrtf(var + BN_EPS);
        float sc = gamma[t] * inv;
        ss[t] = sc;
        ss[128 + t] = beta[t] - mean * sc;
    }
    __syncthreads();
    for (int i = blockIdx.x * 256 + t; i < total4; i += gridDim.x * 256) {
        int cg = i & 31;
        float4 v = ((const float4*)h)[i];
        float4 sc = *(const float4*)&ss[cg * 4];
        float4 sh = *(const float4*)&ss[128 + cg * 4];
        float r0 = fmaxf(fmaf(v.x, sc.x, sh.x), 0.f);
        float r1 = fmaxf(fmaf(v.y, sc.y, sh.y), 0.f);
        float r2 = fmaxf(fmaf(v.z, sc.z, sh.z), 0.f);
        float r3 = fmaxf(fmaf(v.w, sc.w, sh.w), 0.f);
        uint2 o;
        o.x = pack2(r0, r1);
        o.y = pack2(r2, r3);
        ((uint2*)hb)[i] = o;
    }
}

// final BN, fp32 in-place on d_out, finalize inlined
__global__ void bn_apply_kernel(float* __restrict__ h,
                                const float* __restrict__ stats,
                                const float* __restrict__ gamma,
                                const float* __restrict__ beta,
                                float inv_n, int total4) {
    __shared__ float ss[256];
    int t = threadIdx.x;
    if (t < 128) {
        float mean = stats[t] * inv_n;
        float var = stats[128 + t] * inv_n - mean * mean;
        float inv = 1.0f / sqrtf(var + BN_EPS);
        float sc = gamma[t] * inv;
        ss[t] = sc;
        ss[128 + t] = beta[t] - mean * sc;
    }
    __syncthreads();
    for (int i = blockIdx.x * 256 + t; i < total4; i += gridDim.x * 256) {
        int cg = i & 31;
        float4 v = ((float4*)h)[i];
        float4 sc = *(const float4*)&ss[cg * 4];
        float4 sh = *(const float4*)&ss[128 + cg * 4];
        v.x = fmaf(v.x, sc.x, sh.x);
        v.y = fmaf(v.y, sc.y, sh.y);
        v.z = fmaf(v.z, sc.z, sh.z);
        v.w = fmaf(v.w, sc.w, sh.w);
        ((float4*)h)[i] = v;
    }
}

// ---------------------------------------------------------------------------
extern "C" void kernel_launch(void* const* d_in, const int* in_sizes, int n_in,
                              void* d_out, int out_size, void* d_ws, size_t ws_size,
                              hipStream_t stream) {
    const float* x      = (const float*)d_in[0];
    const int*   ei     = (const int*)d_in[1];
    const float* W_l0   = (const float*)d_in[2];
    const float* b_l0   = (const float*)d_in[3];
    const float* W_r0   = (const float*)d_in[4];
    const float* gamma0 = (const float*)d_in[5];
    const float* beta0  = (const float*)d_in[6];
    const float* W_l1   = (const float*)d_in[7];
    const float* b_l1   = (const float*)d_in[8];
    const float* W_r1   = (const float*)d_in[9];
    const float* gamma1 = (const float*)d_in[10];
    const float* beta1  = (const float*)d_in[11];

    const int* src = ei;
    const int* dst = ei + N_EDGES;

    char* w = (char*)d_ws;
    auto alloc = [&](size_t bytes) {
        void* p = (void*)w;
        w += (bytes + 255) & ~(size_t)255;
        return p;
    };
    // zero-init span: stats0, stats1, bcount allocated contiguously
    char* zbase    = w;
    float* stats0  = (float*)alloc(sizeof(float) * 256);
    float* stats1  = (float*)alloc(sizeof(float) * 256);
    int* bcount    = (int*)alloc(sizeof(int) * BUCKS);
    size_t zbytes  = (size_t)(w - zbase);

    int* bbase     = (int*)alloc(sizeof(int) * (BUCKS + 1));
    int* bcursor   = (int*)alloc(sizeof(int) * BUCKS);
    uint* ebuf     = (uint*)alloc(sizeof(uint) * N_EDGES);
    u16* xb        = (u16*)alloc(sizeof(u16) * (size_t)NPAD * 128);
    u16* hb        = (u16*)alloc(sizeof(u16) * (size_t)NPAD * 128);
    u16* aggb      = (u16*)alloc(sizeof(u16) * (size_t)NPAD * 128);
    u16* Wt        = (u16*)alloc(sizeof(u16) * 4 * 16384);
    float* outp    = (float*)d_out;   // fp32 scratch for layer-0 pre-BN

    hipMemsetAsync(zbase, 0, zbytes, stream);

    const int EB = (N_EDGES + 255) / 256;
    const float inv_n = 1.0f / (float)N_NODES;
    const int total4 = N_NODES * HID / 4;
    const int GB = NPAD / 64;

    // bucketed edge organization + casts
    bucket_hist<<<(N_EDGES + 8191) / 8192, 1024, 0, stream>>>(dst, bcount);
    scan_buckets<<<1, 1024, 0, stream>>>(bcount, bbase, bcursor);
    bucket_scatter<<<EB, 256, 0, stream>>>(src, dst, bcursor, ebuf);
    cast_x_kernel<<<(N_NODES * 128 + 255) / 256, 256, 0, stream>>>(x, xb);
    cast_w_kernel<<<dim3(64, 4), 256, 0, stream>>>(W_l0, W_r0, W_l1, W_r1, Wt);

    // Layer 0
    agg_fused<<<BUCKS, 512, 0, stream>>>(ebuf, bbase, xb, aggb);
    gemm_mfma<<<GB, 256, 0, stream>>>(aggb, xb, Wt, Wt + 16384, b_l0, outp, N_NODES);
    stats_kernel<<<128, 256, 0, stream>>>(outp, stats0, N_NODES);
    bn_relu_cast_kernel<<<2048, 256, 0, stream>>>(outp, stats0, gamma0, beta0, hb, inv_n, total4);

    // Layer 1
    agg_fused<<<BUCKS, 512, 0, stream>>>(ebuf, bbase, hb, aggb);
    gemm_mfma<<<GB, 256, 0, stream>>>(aggb, hb, Wt + 2 * 16384, Wt + 3 * 16384, b_l1, outp, N_NODES);
    stats_kernel<<<128, 256, 0, stream>>>(outp, stats1, N_NODES);
    bn_apply_kernel<<<2048, 256, 0, stream>>>(outp, stats1, gamma1, beta1, inv_n, total4);
}

// Round 5
// 266.533 us; speedup vs baseline: 1.6927x; 1.6927x over previous
//
#include <hip/hip_runtime.h>
#include <hip/hip_bf16.h>

#define N_NODES 50000
#define N_EDGES 800000
#define NPAD    50048          // 782 * 64, so GEMM A-staging never reads OOB
#define IN_DIM  100
#define HID     128
#define BN_EPS  1e-5f

#define BSHIFT  6
#define BUCKS   782            // ceil(50000 / 64)
#define BSTRIDE 2048           // fixed slots per bucket in ebuf (mean 1024, 32 sigma)
#define BCAP    2048           // LDS edge capacity per bucket in agg_fused

typedef unsigned int uint;
typedef unsigned short u16;
typedef __attribute__((ext_vector_type(8))) unsigned short us8;
typedef __attribute__((ext_vector_type(8))) short s8;      // bf16 MFMA frag
typedef __attribute__((ext_vector_type(4))) float f4;

__device__ __forceinline__ u16 f2bf(float f) {
    uint u = __builtin_bit_cast(uint, f);
    uint r = (u + 0x7FFFu + ((u >> 16) & 1u)) >> 16;   // RNE
    return (u16)r;
}
__device__ __forceinline__ uint pack2(float a, float b) {
    return (uint)f2bf(a) | ((uint)f2bf(b) << 16);
}
__device__ __forceinline__ float bflo(uint p) { return __builtin_bit_cast(float, p << 16); }
__device__ __forceinline__ float bfhi(uint p) { return __builtin_bit_cast(float, p & 0xFFFF0000u); }

// ---------------------------------------------------------------------------
// Bucketed edge organization, contention-free-ish:
// fixed per-bucket strides; per-block LDS histogram -> one global reservation
// per (block,bucket) -> LDS-cursor scatter. ~77k global RMWs total (~98/addr).
// ---------------------------------------------------------------------------
__global__ void init_cursor(int* __restrict__ bcursor) {
    int b = blockIdx.x * 256 + threadIdx.x;
    if (b < BUCKS) bcursor[b] = b * BSTRIDE;
}

__global__ __launch_bounds__(1024) void bucket_scatter_blk(
    const int* __restrict__ src, const int* __restrict__ dst,
    int* __restrict__ bcursor, uint* __restrict__ ebuf) {
    __shared__ int h[BUCKS];    // counts, then local cursors
    __shared__ int gb[BUCKS];   // this block's reserved base per bucket
    int t = threadIdx.x;
    for (int i = t; i < BUCKS; i += 1024) h[i] = 0;
    __syncthreads();
    int base = blockIdx.x * 8192;
    int myb[8]; uint myv[8];
    #pragma unroll
    for (int r = 0; r < 8; ++r) {
        int e = base + r * 1024 + t;
        int b = -1; uint val = 0;
        if (e < N_EDGES) {
            int d = dst[e];
            b = d >> BSHIFT;
            val = (uint)src[e] | ((uint)(d & 63) << 16);
            atomicAdd(&h[b], 1);
        }
        myb[r] = b; myv[r] = val;
    }
    __syncthreads();
    for (int i = t; i < BUCKS; i += 1024) {
        int c = h[i];
        gb[i] = c ? atomicAdd(&bcursor[i], c) : 0;
        h[i] = 0;   // reuse as local cursor
    }
    __syncthreads();
    #pragma unroll
    for (int r = 0; r < 8; ++r) {
        int b = myb[r];
        if (b >= 0) {
            int pos = gb[b] + atomicAdd(&h[b], 1);
            ebuf[pos] = myv[r];
        }
    }
}

// ---------------------------------------------------------------------------
// Casts to bf16
// ---------------------------------------------------------------------------
__global__ void cast_x_kernel(const float* __restrict__ x, u16* __restrict__ xb) {
    int idx = blockIdx.x * blockDim.x + threadIdx.x;
    if (idx >= N_NODES * 128) return;
    int row = idx >> 7, k = idx & 127;
    float v = (k < IN_DIM) ? x[row * IN_DIM + k] : 0.f;
    xb[idx] = f2bf(v);
}

// weights: fp32 [Ksrc][128] -> bf16 transposed [128 n][128 k], zero-padded k
__global__ void cast_w_kernel(const float* __restrict__ W_l0, const float* __restrict__ W_r0,
                              const float* __restrict__ W_l1, const float* __restrict__ W_r1,
                              u16* __restrict__ d) {
    int w = blockIdx.y;
    const float* s = (w == 0) ? W_l0 : (w == 1) ? W_r0 : (w == 2) ? W_l1 : W_r1;
    int Ks = (w < 2) ? IN_DIM : HID;
    int idx = blockIdx.x * 256 + threadIdx.x;   // 0..16383
    int n = idx >> 7, k = idx & 127;
    float v = (k < Ks) ? s[k * 128 + n] : 0.f;
    d[w * 16384 + idx] = f2bf(v);
}

// ---------------------------------------------------------------------------
// Fused bucket-local CSR + mean aggregation.
// Block = 512 thr (8 waves) = one bucket of 64 nodes. LDS CSR from ebuf slice,
// then wave-per-node quad-parallel gather (16B/lane uint4 loads).
// ---------------------------------------------------------------------------
__global__ __launch_bounds__(512) void agg_fused(
    const uint* __restrict__ ebuf, const int* __restrict__ bcursor,
    const u16* __restrict__ X, u16* __restrict__ out) {
    __shared__ uint eL[BCAP];
    __shared__ u16 srcL[BCAP];
    __shared__ int cnt[64], ro[65], cur[64];

    int b = blockIdx.x;
    int t = threadIdx.x;
    int beg = b * BSTRIDE;
    int n = bcursor[b] - beg;
    if (n > BCAP) n = BCAP;   // statistically unreachable

    if (t < 64) cnt[t] = 0;
    __syncthreads();
    for (int i = t; i < n; i += 512) {
        uint p = ebuf[beg + i];
        eL[i] = p;
        atomicAdd(&cnt[p >> 16], 1);
    }
    __syncthreads();
    if (t < 64) {
        int v = cnt[t];
        int s = v;
        #pragma unroll
        for (int off = 1; off < 64; off <<= 1) {
            int u = __shfl_up(s, off, 64);
            if (t >= off) s += u;
        }
        ro[t] = s - v;
        cur[t] = s - v;
        if (t == 63) ro[64] = s;
    }
    __syncthreads();
    for (int i = t; i < n; i += 512) {
        uint p = eL[i];
        int pos = atomicAdd(&cur[p >> 16], 1);
        srcL[pos] = (u16)(p & 0xFFFFu);
    }
    __syncthreads();

    int wave = t >> 6, lane = t & 63;
    int quad = lane >> 4, sub = lane & 15;
    #pragma unroll
    for (int ni = 0; ni < 8; ++ni) {
        int nl = wave * 8 + ni;
        int node = b * 64 + nl;
        if (node >= N_NODES) continue;   // wave-uniform
        int rb = ro[nl], re = ro[nl + 1];

        float a0 = 0.f, a1 = 0.f, a2 = 0.f, a3 = 0.f;
        float a4 = 0.f, a5 = 0.f, a6 = 0.f, a7 = 0.f;
        int e = rb;
        for (; e + 8 <= re; e += 8) {
            int s0 = srcL[e + quad];          // LDS broadcast within quad
            int s1 = srcL[e + 4 + quad];
            uint4 v0 = ((const uint4*)(X + (size_t)s0 * 128))[sub];
            uint4 v1 = ((const uint4*)(X + (size_t)s1 * 128))[sub];
            a0 += bflo(v0.x) + bflo(v1.x);
            a1 += bfhi(v0.x) + bfhi(v1.x);
            a2 += bflo(v0.y) + bflo(v1.y);
            a3 += bfhi(v0.y) + bfhi(v1.y);
            a4 += bflo(v0.z) + bflo(v1.z);
            a5 += bfhi(v0.z) + bfhi(v1.z);
            a6 += bflo(v0.w) + bflo(v1.w);
            a7 += bfhi(v0.w) + bfhi(v1.w);
        }
        for (; e < re; e += 4) {
            int ee = e + quad;
            if (ee < re) {
                int s0 = srcL[ee];
                uint4 v0 = ((const uint4*)(X + (size_t)s0 * 128))[sub];
                a0 += bflo(v0.x); a1 += bfhi(v0.x);
                a2 += bflo(v0.y); a3 += bfhi(v0.y);
                a4 += bflo(v0.z); a5 += bfhi(v0.z);
                a6 += bflo(v0.w); a7 += bfhi(v0.w);
            }
        }
        #pragma unroll
        for (int m = 16; m <= 32; m <<= 1) {
            a0 += __shfl_xor(a0, m, 64); a1 += __shfl_xor(a1, m, 64);
            a2 += __shfl_xor(a2, m, 64); a3 += __shfl_xor(a3, m, 64);
            a4 += __shfl_xor(a4, m, 64); a5 += __shfl_xor(a5, m, 64);
            a6 += __shfl_xor(a6, m, 64); a7 += __shfl_xor(a7, m, 64);
        }
        if (quad == 0) {
            float inv = 1.0f / fmaxf((float)(re - rb), 1.0f);
            uint4 o;
            o.x = pack2(a0 * inv, a1 * inv);
            o.y = pack2(a2 * inv, a3 * inv);
            o.z = pack2(a4 * inv, a5 * inv);
            o.w = pack2(a6 * inv, a7 * inv);
            ((uint4*)(out + (size_t)node * 128))[sub] = o;
        }
    }
}

// ---------------------------------------------------------------------------
// Dual-input bf16 MFMA GEMM (unchanged; verified fast)
// ---------------------------------------------------------------------------
__global__ __launch_bounds__(256) void gemm_mfma(
    const u16* __restrict__ A1, const u16* __restrict__ A2,
    const u16* __restrict__ Wt1, const u16* __restrict__ Wt2,
    const float* __restrict__ bias, float* __restrict__ out, int M) {
    __shared__ u16 Als[64][32];
    __shared__ u16 Bls[128][32];

    int tid = threadIdx.x;
    int wave = tid >> 6;
    int lane = tid & 63;
    int l16 = lane & 15;
    int quad = lane >> 4;
    int rm = (wave & 1) * 32;
    int cn = (wave >> 1) * 64;
    int row0 = blockIdx.x * 64;

    f4 acc[2][4];
    #pragma unroll
    for (int i = 0; i < 2; i++)
        #pragma unroll
        for (int j = 0; j < 4; j++)
            acc[i][j] = (f4)0.f;

    #pragma unroll
    for (int phase = 0; phase < 2; ++phase) {
        const u16* A  = phase ? A2 : A1;
        const u16* Wt = phase ? Wt2 : Wt1;
        #pragma unroll
        for (int k0 = 0; k0 < 128; k0 += 32) {
            __syncthreads();
            {
                int r = tid >> 2, c = tid & 3;
                us8 v = *(const us8*)(A + (size_t)(row0 + r) * 128 + k0 + c * 8);
                *(us8*)&Als[r][c * 8] = v;
            }
            #pragma unroll
            for (int rep = 0; rep < 2; ++rep) {
                int idx = rep * 256 + tid;
                int nn = idx >> 2, c = idx & 3;
                us8 v = *(const us8*)(Wt + nn * 128 + k0 + c * 8);
                *(us8*)&Bls[nn][c * 8] = v;
            }
            __syncthreads();
            s8 af[2], bfr[4];
            #pragma unroll
            for (int mt = 0; mt < 2; ++mt)
                af[mt] = *(const s8*)&Als[rm + mt * 16 + l16][quad * 8];
            #pragma unroll
            for (int nt = 0; nt < 4; ++nt)
                bfr[nt] = *(const s8*)&Bls[cn + nt * 16 + l16][quad * 8];
            #pragma unroll
            for (int mt = 0; mt < 2; ++mt)
                #pragma unroll
                for (int nt = 0; nt < 4; ++nt)
                    acc[mt][nt] = __builtin_amdgcn_mfma_f32_16x16x32_bf16(
                        af[mt], bfr[nt], acc[mt][nt], 0, 0, 0);
        }
    }

    #pragma unroll
    for (int mt = 0; mt < 2; ++mt) {
        #pragma unroll
        for (int nt = 0; nt < 4; ++nt) {
            int col = cn + nt * 16 + l16;
            float b = bias[col];
            #pragma unroll
            for (int r = 0; r < 4; ++r) {
                int row = row0 + rm + mt * 16 + quad * 4 + r;
                if (row < M)
                    out[(size_t)row * 128 + col] = acc[mt][nt][r] + b;
            }
        }
    }
}

// ---------------------------------------------------------------------------
// BatchNorm stats: float4 reads, LDS tree, 8 atomics per block
// ---------------------------------------------------------------------------
__global__ void stats_kernel(const float* __restrict__ h, float* __restrict__ stats, int M) {
    __shared__ float l1[256 * 4], l2[256 * 4];
    int t = threadIdx.x;             // 256
    int tg = t >> 5, c = t & 31;
    float s1x = 0.f, s1y = 0.f, s1z = 0.f, s1w = 0.f;
    float s2x = 0.f, s2y = 0.f, s2z = 0.f, s2w = 0.f;
    for (int n = blockIdx.x * 8 + tg; n < M; n += gridDim.x * 8) {
        float4 v = ((const float4*)(h + (size_t)n * 128))[c];
        s1x += v.x; s1y += v.y; s1z += v.z; s1w += v.w;
        s2x = fmaf(v.x, v.x, s2x); s2y = fmaf(v.y, v.y, s2y);
        s2z = fmaf(v.z, v.z, s2z); s2w = fmaf(v.w, v.w, s2w);
    }
    l1[t * 4 + 0] = s1x; l1[t * 4 + 1] = s1y; l1[t * 4 + 2] = s1z; l1[t * 4 + 3] = s1w;
    l2[t * 4 + 0] = s2x; l2[t * 4 + 1] = s2y; l2[t * 4 + 2] = s2z; l2[t * 4 + 3] = s2w;
    __syncthreads();
    #pragma unroll
    for (int stride = 128; stride >= 64; stride >>= 1) {
        if (t < stride) {
            #pragma unroll
            for (int j = 0; j < 4; j++) {
                l1[t * 4 + j] += l1[(t + stride) * 4 + j];
                l2[t * 4 + j] += l2[(t + stride) * 4 + j];
            }
        }
        __syncthreads();
    }
    if (t < 32) {
        #pragma unroll
        for (int j = 0; j < 4; j++) {
            float v1 = l1[t * 4 + j] + l1[(t + 32) * 4 + j];
            float v2 = l2[t * 4 + j] + l2[(t + 32) * 4 + j];
            atomicAdd(&stats[t * 4 + j], v1);
            atomicAdd(&stats[128 + t * 4 + j], v2);
        }
    }
}

// BN(+ReLU)+cast to bf16, finalize inlined (layer-0 -> layer-1 handoff)
__global__ void bn_relu_cast_kernel(const float* __restrict__ h,
                                    const float* __restrict__ stats,
                                    const float* __restrict__ gamma,
                                    const float* __restrict__ beta,
                                    u16* __restrict__ hb, float inv_n, int total4) {
    __shared__ float ss[256];
    int t = threadIdx.x;
    if (t < 128) {
        float mean = stats[t] * inv_n;
        float var = stats[128 + t] * inv_n - mean * mean;
        float inv = 1.0f / sqrtf(var + BN_EPS);
        float sc = gamma[t] * inv;
        ss[t] = sc;
        ss[128 + t] = beta[t] - mean * sc;
    }
    __syncthreads();
    for (int i = blockIdx.x * 256 + t; i < total4; i += gridDim.x * 256) {
        int cg = i & 31;
        float4 v = ((const float4*)h)[i];
        float4 sc = *(const float4*)&ss[cg * 4];
        float4 sh = *(const float4*)&ss[128 + cg * 4];
        float r0 = fmaxf(fmaf(v.x, sc.x, sh.x), 0.f);
        float r1 = fmaxf(fmaf(v.y, sc.y, sh.y), 0.f);
        float r2 = fmaxf(fmaf(v.z, sc.z, sh.z), 0.f);
        float r3 = fmaxf(fmaf(v.w, sc.w, sh.w), 0.f);
        uint2 o;
        o.x = pack2(r0, r1);
        o.y = pack2(r2, r3);
        ((uint2*)hb)[i] = o;
    }
}

// final BN, fp32 in-place on d_out, finalize inlined
__global__ void bn_apply_kernel(float* __restrict__ h,
                                const float* __restrict__ stats,
                                const float* __restrict__ gamma,
                                const float* __restrict__ beta,
                                float inv_n, int total4) {
    __shared__ float ss[256];
    int t = threadIdx.x;
    if (t < 128) {
        float mean = stats[t] * inv_n;
        float var = stats[128 + t] * inv_n - mean * mean;
        float inv = 1.0f / sqrtf(var + BN_EPS);
        float sc = gamma[t] * inv;
        ss[t] = sc;
        ss[128 + t] = beta[t] - mean * sc;
    }
    __syncthreads();
    for (int i = blockIdx.x * 256 + t; i < total4; i += gridDim.x * 256) {
        int cg = i & 31;
        float4 v = ((float4*)h)[i];
        float4 sc = *(const float4*)&ss[cg * 4];
        float4 sh = *(const float4*)&ss[128 + cg * 4];
        v.x = fmaf(v.x, sc.x, sh.x);
        v.y = fmaf(v.y, sc.y, sh.y);
        v.z = fmaf(v.z, sc.z, sh.z);
        v.w = fmaf(v.w, sc.w, sh.w);
        ((float4*)h)[i] = v;
    }
}

// ---------------------------------------------------------------------------
extern "C" void kernel_launch(void* const* d_in, const int* in_sizes, int n_in,
                              void* d_out, int out_size, void* d_ws, size_t ws_size,
                              hipStream_t stream) {
    const float* x      = (const float*)d_in[0];
    const int*   ei     = (const int*)d_in[1];
    const float* W_l0   = (const float*)d_in[2];
    const float* b_l0   = (const float*)d_in[3];
    const float* W_r0   = (const float*)d_in[4];
    const float* gamma0 = (const float*)d_in[5];
    const float* beta0  = (const float*)d_in[6];
    const float* W_l1   = (const float*)d_in[7];
    const float* b_l1   = (const float*)d_in[8];
    const float* W_r1   = (const float*)d_in[9];
    const float* gamma1 = (const float*)d_in[10];
    const float* beta1  = (const float*)d_in[11];

    const int* src = ei;
    const int* dst = ei + N_EDGES;

    char* w = (char*)d_ws;
    auto alloc = [&](size_t bytes) {
        void* p = (void*)w;
        w += (bytes + 255) & ~(size_t)255;
        return p;
    };
    // zero-init span: stats0, stats1 contiguous
    char* zbase    = w;
    float* stats0  = (float*)alloc(sizeof(float) * 256);
    float* stats1  = (float*)alloc(sizeof(float) * 256);
    size_t zbytes  = (size_t)(w - zbase);

    int* bcursor   = (int*)alloc(sizeof(int) * BUCKS);
    uint* ebuf     = (uint*)alloc(sizeof(uint) * BUCKS * BSTRIDE);
    u16* xb        = (u16*)alloc(sizeof(u16) * (size_t)NPAD * 128);
    u16* hb        = (u16*)alloc(sizeof(u16) * (size_t)NPAD * 128);
    u16* aggb      = (u16*)alloc(sizeof(u16) * (size_t)NPAD * 128);
    u16* Wt        = (u16*)alloc(sizeof(u16) * 4 * 16384);
    float* outp    = (float*)d_out;   // fp32 scratch for layer-0 pre-BN

    hipMemsetAsync(zbase, 0, zbytes, stream);

    const float inv_n = 1.0f / (float)N_NODES;
    const int total4 = N_NODES * HID / 4;
    const int GB = NPAD / 64;

    // bucketed edge organization + casts
    init_cursor<<<(BUCKS + 255) / 256, 256, 0, stream>>>(bcursor);
    bucket_scatter_blk<<<(N_EDGES + 8191) / 8192, 1024, 0, stream>>>(src, dst, bcursor, ebuf);
    cast_x_kernel<<<(N_NODES * 128 + 255) / 256, 256, 0, stream>>>(x, xb);
    cast_w_kernel<<<dim3(64, 4), 256, 0, stream>>>(W_l0, W_r0, W_l1, W_r1, Wt);

    // Layer 0
    agg_fused<<<BUCKS, 512, 0, stream>>>(ebuf, bcursor, xb, aggb);
    gemm_mfma<<<GB, 256, 0, stream>>>(aggb, xb, Wt, Wt + 16384, b_l0, outp, N_NODES);
    stats_kernel<<<128, 256, 0, stream>>>(outp, stats0, N_NODES);
    bn_relu_cast_kernel<<<2048, 256, 0, stream>>>(outp, stats0, gamma0, beta0, hb, inv_n, total4);

    // Layer 1
    agg_fused<<<BUCKS, 512, 0, stream>>>(ebuf, bcursor, hb, aggb);
    gemm_mfma<<<GB, 256, 0, stream>>>(aggb, hb, Wt + 2 * 16384, Wt + 3 * 16384, b_l1, outp, N_NODES);
    stats_kernel<<<128, 256, 0, stream>>>(outp, stats1, N_NODES);
    bn_apply_kernel<<<2048, 256, 0, stream>>>(outp, stats1, gamma1, beta1, inv_n, total4);
}